// Round 18
// baseline (311.172 us; speedup 1.0000x reference)
//
#include <hip/hip_runtime.h>
#include <math.h>

#define N 8192
#define C 10
#define NUM_ITERS 5
#define FBLOCK 1024        /* 16 waves, 1 block/CU, 4 waves/SIMD */
#define IBLK 32            /* i's per block */
#define NBLK (N / IBLK)    /* 256 blocks = 1 per CU */
#define JW (N / 16)        /* 512 j's per wave */
#define NS (JW / 32)       /* 16 s-iters per wave, 32 j's each */
#define LOG2E 1.44269504088896340736f
#define C3 (LOG2E / 64.0f)

typedef _Float16 half8 __attribute__((ext_vector_type(8)));
typedef _Float16 half4 __attribute__((ext_vector_type(4)));
typedef _Float16 half2 __attribute__((ext_vector_type(2)));
typedef float f32x4 __attribute__((ext_vector_type(4)));
typedef float f32x16 __attribute__((ext_vector_type(16)));
typedef unsigned int uint4v __attribute__((ext_vector_type(4)));

// ws layout:
//   ajs half8[N] 128KB ; ajb half8[N] 128KB
//   pf0/pf1 f16[N/16][16][16] : probs, J-TILED (tile jt, row c, col j&15)
#define WS_AJS 0
#define WS_AJB (N * 16)
#define WS_PF0 (N * 32)
#define WS_PF1 (N * 64)
#define PFIDX(n, c) ((((n) >> 4) * 16 + (c)) * 16 + ((n) & 15))

static __device__ __forceinline__ unsigned int pkexp(float a, float b) {
    float ea = __builtin_amdgcn_exp2f(a);
    float eb = __builtin_amdgcn_exp2f(b);
    return __builtin_bit_cast(unsigned int, __builtin_amdgcn_cvt_pkrtz(ea, eb));
}

static __device__ __forceinline__ half8 mk8(unsigned int a, unsigned int b,
                                            unsigned int c, unsigned int d) {
    uint4v v = {a, b, c, d};
    return __builtin_bit_cast(half8, v);
}

// once per launch: aug features + softmax(unaries) -> pf0 (tiled); zero rows 10..15 both
__global__ __launch_bounds__(256) void init_kernel(
    const float* __restrict__ unaries, const float* __restrict__ feat,
    half8* __restrict__ ajs8, half8* __restrict__ ajb8,
    _Float16* __restrict__ pf0, _Float16* __restrict__ pf1) {
    int n = blockIdx.x * 256 + threadIdx.x;
    float f6[6];
#pragma unroll
    for (int d = 0; d < 6; ++d) f6[d] = feat[d * N + n];
    float h3 = 0.5f * (f6[0] * f6[0] + f6[1] * f6[1] + f6[2] * f6[2]);
    float h6v = h3 + 0.5f * (f6[3] * f6[3] + f6[4] * f6[4] + f6[5] * f6[5]);
    half8 a = {};
    a[0] = (_Float16)(f6[0] * C3);
    a[1] = (_Float16)(f6[1] * C3);
    a[2] = (_Float16)(f6[2] * C3);
    a[6] = (_Float16)(-h3 * C3);
    a[7] = (_Float16)1.0f;
    ajs8[n] = a;
    half8 b;
#pragma unroll
    for (int d = 0; d < 6; ++d) b[d] = (_Float16)(f6[d] * LOG2E);
    b[6] = (_Float16)(-h6v * LOG2E);
    b[7] = (_Float16)1.0f;
    ajb8[n] = b;

    float q[C];
#pragma unroll
    for (int c = 0; c < C; ++c) q[c] = unaries[c * N + n];
    float m = q[0];
#pragma unroll
    for (int c = 1; c < C; ++c) m = fmaxf(m, q[c]);
    float e[C], s = 0.0f;
#pragma unroll
    for (int c = 0; c < C; ++c) {
        e[c] = __builtin_amdgcn_exp2f((q[c] - m) * LOG2E);
        s += e[c];
    }
    float inv = 1.0f / s;
#pragma unroll
    for (int c = 0; c < C; ++c) pf0[PFIDX(n, c)] = (_Float16)(e[c] * inv);
#pragma unroll
    for (int c = C; c < 16; ++c) {
        pf0[PFIDX(n, c)] = (_Float16)0.0f;
        pf1[PFIDX(n, c)] = (_Float16)0.0f;
    }
}

// operand bundle for one s-iter (named members only -> registers)
struct Ops { half8 A_s, A_b, A20, A21; };

// one dispatch per CRF iteration. Register-only main loop (R17 math, verified),
// SOFTWARE-PIPELINED one s-iter deep: per phase the program order is
//   pkexp(d1[k]) -> G2[k] -> G1[k+1] -> load ops[k+2]
// so every consumer's input is >=1 phase old; trans/MFMA/VMEM streams decouple.
__global__ __launch_bounds__(FBLOCK, 4) void fused_kernel(
    const float* __restrict__ unaries, const float* __restrict__ feat,
    const float* __restrict__ SW, const float* __restrict__ BW,
    const float* __restrict__ CM,
    const char* __restrict__ ajs_c, const char* __restrict__ ajb_c,
    const _Float16* __restrict__ pf_in, _Float16* __restrict__ pf_out,
    float* __restrict__ out, int is_last) {
    __shared__ float rbuf[16 * 640];   // 40 KB, epilogue only
    int t = threadIdx.x;
    int i0 = blockIdx.x * IBLK;
    int lane = t & 63;
    int w = t >> 6;
    int li = lane & 31;      // i (G1/G2 D col) or j (G1 A row) within 32
    int hs = lane >> 5;      // K-half select
    int cr = li & 15;        // p-row for G2 A-operand (c-rows 16..31 discarded)
    const f32x16 zero16 = {};

    // ---- B1 fragments (G1 B-operand): lane holds aug[4hs..4hs+3] of i=i0+li ----
    half8 b1s, b1b;
    {
        int i = i0 + li;
        float g0 = feat[0 * N + i], g1 = feat[1 * N + i], g2 = feat[2 * N + i];
        float g3 = feat[3 * N + i], g4 = feat[4 * N + i], g5 = feat[5 * N + i];
        float h3 = 0.5f * (g0 * g0 + g1 * g1 + g2 * g2);
        float h6v = h3 + 0.5f * (g3 * g3 + g4 * g4 + g5 * g5);
        half4 slo = {(_Float16)g0, (_Float16)g1, (_Float16)g2, (_Float16)0.0f};
        half4 shi = {(_Float16)0.0f, (_Float16)0.0f, (_Float16)1.0f, (_Float16)(-h3 * C3)};
        half4 blo = {(_Float16)g0, (_Float16)g1, (_Float16)g2, (_Float16)g3};
        half4 bhi = {(_Float16)g4, (_Float16)g5, (_Float16)1.0f, (_Float16)(-h6v * LOG2E)};
        half4 sv = hs ? shi : slo;
        half4 bv = hs ? bhi : blo;
        half8 t1 = {sv[0], sv[1], sv[2], sv[3], (_Float16)0.0f, (_Float16)0.0f,
                    (_Float16)0.0f, (_Float16)0.0f};
        half8 t2 = {bv[0], bv[1], bv[2], bv[3], (_Float16)0.0f, (_Float16)0.0f,
                    (_Float16)0.0f, (_Float16)0.0f};
        b1s = t1;
        b1b = t2;
    }

    f32x16 acc_s = zero16, acc_b = zero16;
    int jw = w * JW;

    // convoy-breaking wave stagger (no sync points in main loop -> persists)
    {
        int ph = w & 3;
        if (ph == 1) __builtin_amdgcn_s_sleep(2);
        else if (ph == 2) __builtin_amdgcn_s_sleep(4);
        else if (ph == 3) __builtin_amdgcn_s_sleep(6);
    }

    // load operands for s-iter K (wrap: harmless L2-hit reload at the tail)
#define LOADOPS(O, K)                                                          \
    {                                                                          \
        int _j0 = jw + ((K) & (NS - 1)) * 32;                                  \
        int _jt = _j0 >> 4;                                                    \
        half4 _avs = *(const half4*)(ajs_c + (size_t)(_j0 + li) * 16 + hs * 8);\
        half4 _avb = *(const half4*)(ajb_c + (size_t)(_j0 + li) * 16 + hs * 8);\
        const _Float16* _p0 = pf_in + (size_t)(_jt * 16 + cr) * 16;            \
        const _Float16* _p1 = pf_in + (size_t)((_jt + 1) * 16 + cr) * 16;      \
        half4 _p0l = *(const half4*)&_p0[4 * hs];                              \
        half4 _p0h = *(const half4*)&_p0[8 + 4 * hs];                          \
        half4 _p1l = *(const half4*)&_p1[4 * hs];                              \
        half4 _p1h = *(const half4*)&_p1[8 + 4 * hs];                          \
        half8 _as = {_avs[0], _avs[1], _avs[2], _avs[3], (_Float16)0.0f,       \
                     (_Float16)0.0f, (_Float16)0.0f, (_Float16)0.0f};          \
        half8 _ab = {_avb[0], _avb[1], _avb[2], _avb[3], (_Float16)0.0f,       \
                     (_Float16)0.0f, (_Float16)0.0f, (_Float16)0.0f};          \
        half8 _a20 = {_p0l[0], _p0l[1], _p0l[2], _p0l[3],                      \
                      _p0h[0], _p0h[1], _p0h[2], _p0h[3]};                     \
        half8 _a21 = {_p1l[0], _p1l[1], _p1l[2], _p1l[3],                      \
                      _p1h[0], _p1h[1], _p1h[2], _p1h[3]};                     \
        O.A_s = _as; O.A_b = _ab; O.A20 = _a20; O.A21 = _a21;                  \
    }
#define G1(DS, DB, O)                                                          \
    {                                                                          \
        DS = __builtin_amdgcn_mfma_f32_32x32x16_f16(O.A_s, b1s, zero16, 0, 0, 0); \
        DB = __builtin_amdgcn_mfma_f32_32x32x16_f16(O.A_b, b1b, zero16, 0, 0, 0); \
    }
    // pkexp(d1) -> B-frags, then G2 accumulate (consumes O's A2 frags)
#define PKG2(DS, DB, O)                                                        \
    {                                                                          \
        half8 _Bs0 = mk8(pkexp(DS[0], DS[1]), pkexp(DS[2], DS[3]),             \
                         pkexp(DS[4], DS[5]), pkexp(DS[6], DS[7]));            \
        half8 _Bs1 = mk8(pkexp(DS[8], DS[9]), pkexp(DS[10], DS[11]),           \
                         pkexp(DS[12], DS[13]), pkexp(DS[14], DS[15]));        \
        half8 _Bb0 = mk8(pkexp(DB[0], DB[1]), pkexp(DB[2], DB[3]),             \
                         pkexp(DB[4], DB[5]), pkexp(DB[6], DB[7]));            \
        half8 _Bb1 = mk8(pkexp(DB[8], DB[9]), pkexp(DB[10], DB[11]),           \
                         pkexp(DB[12], DB[13]), pkexp(DB[14], DB[15]));        \
        __builtin_amdgcn_s_setprio(1);                                         \
        acc_s = __builtin_amdgcn_mfma_f32_32x32x16_f16(O.A20, _Bs0, acc_s, 0, 0, 0); \
        acc_s = __builtin_amdgcn_mfma_f32_32x32x16_f16(O.A21, _Bs1, acc_s, 0, 0, 0); \
        acc_b = __builtin_amdgcn_mfma_f32_32x32x16_f16(O.A20, _Bb0, acc_b, 0, 0, 0); \
        acc_b = __builtin_amdgcn_mfma_f32_32x32x16_f16(O.A21, _Bb1, acc_b, 0, 0, 0); \
        __builtin_amdgcn_s_setprio(0);                                         \
    }

    Ops opA, opB;
    f32x16 dA, dB;
    // ---- prologue: ops[0], ops[1]; d1[0] ----
    LOADOPS(opA, 0);
    LOADOPS(opB, 1);
    G1(dA, dB, opA);   // NOTE: dA,dB here are d1s,d1b of s-iter 0
    // rename for clarity: keep dA=spatial, dB=bilateral of CURRENT s-iter; we
    // alternate ops slots only. d-pair always belongs to the s-iter being
    // finished; next G1 writes the OTHER d-pair.
    f32x16 eA, eB;     // d1 pair of the NEXT s-iter

    // steady state: 7 x 2 s-iters (0..13)
    for (int m = 0; m < 7; ++m) {
        // s-iter 2m: finish (pkexp+G2 on dA/dB, opA); produce next (G1 -> eA/eB from opB); reload opA
        G1(eA, eB, opB);
        PKG2(dA, dB, opA);
        LOADOPS(opA, 2 * m + 2);
        // s-iter 2m+1: finish (eA/eB, opB); produce next (dA/dB from opA); reload opB
        G1(dA, dB, opA);
        PKG2(eA, eB, opB);
        LOADOPS(opB, 2 * m + 3);
    }
    // ---- epilogue: s-iters 14, 15 ----
    G1(eA, eB, opB);
    PKG2(dA, dB, opA);
    PKG2(eA, eB, opB);

#undef LOADOPS
#undef G1
#undef PKG2

    // ---- dump valid acc rows to rbuf[w][filter][c][i] (c = (r&3)+8(r>>2)+4hs) ----
    {
        float* rb = rbuf + w * 640;
        if (hs == 0) {
#pragma unroll
            for (int r = 0; r < 4; ++r) {
                rb[r * 32 + li]       = acc_s[r];
                rb[320 + r * 32 + li] = acc_b[r];
            }
            rb[8 * 32 + li] = acc_s[4];
            rb[9 * 32 + li] = acc_s[5];
            rb[320 + 8 * 32 + li] = acc_b[4];
            rb[320 + 9 * 32 + li] = acc_b[5];
        } else {
#pragma unroll
            for (int r = 0; r < 4; ++r) {
                rb[(4 + r) * 32 + li]       = acc_s[r];
                rb[320 + (4 + r) * 32 + li] = acc_b[r];
            }
        }
    }
    __syncthreads();
    if (t < 640) {
        float tot = 0.f;
#pragma unroll
        for (int w2 = 0; w2 < 16; ++w2) tot += rbuf[w2 * 640 + t];
        rbuf[t] = tot;   // slot t read only by thread t (w2=0 term)
    }
    __syncthreads();

    // ---- combine + compatibility + softmax for this block's 32 i's ----
    if (t < IBLK) {
        int i = i0 + t;
        float sp[C], bl[C];
#pragma unroll
        for (int c = 0; c < C; ++c) {
            sp[c] = rbuf[c * 32 + t];
            bl[c] = rbuf[320 + c * 32 + t];
        }
        float msg[C];
#pragma unroll
        for (int c = 0; c < C; ++c) {
            float m = 0.f;
#pragma unroll
            for (int kk = 0; kk < C; ++kk)
                m += SW[c * C + kk] * sp[kk] + BW[c * C + kk] * bl[kk];
            msg[c] = m;
        }
        float qq[C];
#pragma unroll
        for (int c = 0; c < C; ++c) {
            float pw = 0.f;
#pragma unroll
            for (int kk = 0; kk < C; ++kk) pw += CM[c * C + kk] * msg[kk];
            qq[c] = unaries[c * N + i] - pw;
        }
        if (is_last) {
#pragma unroll
            for (int c = 0; c < C; ++c) out[c * N + i] = qq[c];
        } else {
            float m = qq[0];
#pragma unroll
            for (int c = 1; c < C; ++c) m = fmaxf(m, qq[c]);
            float e[C], s = 0.0f;
#pragma unroll
            for (int c = 0; c < C; ++c) {
                e[c] = __builtin_amdgcn_exp2f((qq[c] - m) * LOG2E);
                s += e[c];
            }
            float inv = 1.0f / s;
#pragma unroll
            for (int c = 0; c < C; ++c) pf_out[PFIDX(i, c)] = (_Float16)(e[c] * inv);
        }
    }
}

extern "C" void kernel_launch(void* const* d_in, const int* in_sizes, int n_in,
                              void* d_out, int out_size, void* d_ws, size_t ws_size,
                              hipStream_t stream) {
    const float* unaries = (const float*)d_in[0];   // [10, 8192]
    const float* feat    = (const float*)d_in[1];   // [6, 8192]
    const float* SW      = (const float*)d_in[2];   // [10,10]
    const float* BW      = (const float*)d_in[3];   // [10,10]
    const float* CM      = (const float*)d_in[4];   // [10,10]
    float* out = (float*)d_out;

    char* ws = (char*)d_ws;
    half8* ajs    = (half8*)(ws + WS_AJS);
    half8* ajb    = (half8*)(ws + WS_AJB);
    _Float16* pf0 = (_Float16*)(ws + WS_PF0);
    _Float16* pf1 = (_Float16*)(ws + WS_PF1);

    init_kernel<<<N / 256, 256, 0, stream>>>(unaries, feat, ajs, ajb, pf0, pf1);
    const _Float16* pin = pf0;
    _Float16* pout = pf1;
    for (int it = 1; it <= NUM_ITERS; ++it) {
        fused_kernel<<<NBLK, FBLOCK, 0, stream>>>(
            unaries, feat, SW, BW, CM, (const char*)ajs, (const char*)ajb,
            pin, pout, out, it == NUM_ITERS ? 1 : 0);
        const _Float16* tmp = pout;
        pout = (_Float16*)pin;
        pin = tmp;
    }
}

// Round 19
// 156.054 us; speedup vs baseline: 1.9940x; 1.9940x over previous
//
#include <hip/hip_runtime.h>
#include <math.h>

#define N 8192
#define C 10
#define NUM_ITERS 5
#define FBLOCK 1024        /* 16 waves, 1 block/CU, 4 waves/SIMD */
#define IBLK 32            /* i's per block */
#define NBLK (N / IBLK)    /* 256 blocks = 1 per CU */
#define JW (N / 16)        /* 512 j's per wave */
#define NS (JW / 32)       /* 16 s-iters per wave, 32 j's each */
#define LOG2E 1.44269504088896340736f
#define C3 (LOG2E / 64.0f)

typedef _Float16 half8 __attribute__((ext_vector_type(8)));
typedef _Float16 half4 __attribute__((ext_vector_type(4)));
typedef _Float16 half2 __attribute__((ext_vector_type(2)));
typedef float f32x4 __attribute__((ext_vector_type(4)));
typedef float f32x16 __attribute__((ext_vector_type(16)));
typedef unsigned int uint4v __attribute__((ext_vector_type(4)));

// ws layout:
//   ajs half8[N] 128KB ; ajb half8[N] 128KB
//   pf0/pf1 f16[N/16][16][16] : probs, J-TILED (tile jt, row c, col j&15)
#define WS_AJS 0
#define WS_AJB (N * 16)
#define WS_PF0 (N * 32)
#define WS_PF1 (N * 64)
#define PFIDX(n, c) ((((n) >> 4) * 16 + (c)) * 16 + ((n) & 15))

static __device__ __forceinline__ unsigned int pkexp(float a, float b) {
    float ea = __builtin_amdgcn_exp2f(a);
    float eb = __builtin_amdgcn_exp2f(b);
    return __builtin_bit_cast(unsigned int, __builtin_amdgcn_cvt_pkrtz(ea, eb));
}

static __device__ __forceinline__ half8 mk8(unsigned int a, unsigned int b,
                                            unsigned int c, unsigned int d) {
    uint4v v = {a, b, c, d};
    return __builtin_bit_cast(half8, v);
}

// once per launch: aug features + softmax(unaries) -> pf0 (tiled); zero rows 10..15 both
__global__ __launch_bounds__(256) void init_kernel(
    const float* __restrict__ unaries, const float* __restrict__ feat,
    half8* __restrict__ ajs8, half8* __restrict__ ajb8,
    _Float16* __restrict__ pf0, _Float16* __restrict__ pf1) {
    int n = blockIdx.x * 256 + threadIdx.x;
    float f6[6];
#pragma unroll
    for (int d = 0; d < 6; ++d) f6[d] = feat[d * N + n];
    float h3 = 0.5f * (f6[0] * f6[0] + f6[1] * f6[1] + f6[2] * f6[2]);
    float h6v = h3 + 0.5f * (f6[3] * f6[3] + f6[4] * f6[4] + f6[5] * f6[5]);
    half8 a = {};
    a[0] = (_Float16)(f6[0] * C3);
    a[1] = (_Float16)(f6[1] * C3);
    a[2] = (_Float16)(f6[2] * C3);
    a[6] = (_Float16)(-h3 * C3);
    a[7] = (_Float16)1.0f;
    ajs8[n] = a;
    half8 b;
#pragma unroll
    for (int d = 0; d < 6; ++d) b[d] = (_Float16)(f6[d] * LOG2E);
    b[6] = (_Float16)(-h6v * LOG2E);
    b[7] = (_Float16)1.0f;
    ajb8[n] = b;

    float q[C];
#pragma unroll
    for (int c = 0; c < C; ++c) q[c] = unaries[c * N + n];
    float m = q[0];
#pragma unroll
    for (int c = 1; c < C; ++c) m = fmaxf(m, q[c]);
    float e[C], s = 0.0f;
#pragma unroll
    for (int c = 0; c < C; ++c) {
        e[c] = __builtin_amdgcn_exp2f((q[c] - m) * LOG2E);
        s += e[c];
    }
    float inv = 1.0f / s;
#pragma unroll
    for (int c = 0; c < C; ++c) pf0[PFIDX(n, c)] = (_Float16)(e[c] * inv);
#pragma unroll
    for (int c = C; c < 16; ++c) {
        pf0[PFIDX(n, c)] = (_Float16)0.0f;
        pf1[PFIDX(n, c)] = (_Float16)0.0f;
    }
}

// operand bundle for one s-iter (named members only -> registers)
struct Ops { half8 A_s, A_b, A20, A21; };

// one dispatch per CRF iteration. Register-only main loop (R17 math, verified).
// LOAD-ONLY 1-deep prefetch: per s-iter, G1(d, cur) -> issue loads(next) ->
// pkexp+G2(d, cur). Single d-pair live (R18's 2-pair variant spilled: 64 VGPR
// of d-regs blew the 128 cap and caused 55MB/dispatch scratch traffic).
__global__ __launch_bounds__(FBLOCK, 4) void fused_kernel(
    const float* __restrict__ unaries, const float* __restrict__ feat,
    const float* __restrict__ SW, const float* __restrict__ BW,
    const float* __restrict__ CM,
    const char* __restrict__ ajs_c, const char* __restrict__ ajb_c,
    const _Float16* __restrict__ pf_in, _Float16* __restrict__ pf_out,
    float* __restrict__ out, int is_last) {
    __shared__ float rbuf[16 * 640];   // 40 KB, epilogue only
    int t = threadIdx.x;
    int i0 = blockIdx.x * IBLK;
    int lane = t & 63;
    int w = t >> 6;
    int li = lane & 31;      // i (G1/G2 D col) or j (G1 A row) within 32
    int hs = lane >> 5;      // K-half select
    int cr = li & 15;        // p-row for G2 A-operand (c-rows 16..31 discarded)
    const f32x16 zero16 = {};

    // ---- B1 fragments (G1 B-operand): lane holds aug[4hs..4hs+3] of i=i0+li ----
    half8 b1s, b1b;
    {
        int i = i0 + li;
        float g0 = feat[0 * N + i], g1 = feat[1 * N + i], g2 = feat[2 * N + i];
        float g3 = feat[3 * N + i], g4 = feat[4 * N + i], g5 = feat[5 * N + i];
        float h3 = 0.5f * (g0 * g0 + g1 * g1 + g2 * g2);
        float h6v = h3 + 0.5f * (g3 * g3 + g4 * g4 + g5 * g5);
        half4 slo = {(_Float16)g0, (_Float16)g1, (_Float16)g2, (_Float16)0.0f};
        half4 shi = {(_Float16)0.0f, (_Float16)0.0f, (_Float16)1.0f, (_Float16)(-h3 * C3)};
        half4 blo = {(_Float16)g0, (_Float16)g1, (_Float16)g2, (_Float16)g3};
        half4 bhi = {(_Float16)g4, (_Float16)g5, (_Float16)1.0f, (_Float16)(-h6v * LOG2E)};
        half4 sv = hs ? shi : slo;
        half4 bv = hs ? bhi : blo;
        half8 t1 = {sv[0], sv[1], sv[2], sv[3], (_Float16)0.0f, (_Float16)0.0f,
                    (_Float16)0.0f, (_Float16)0.0f};
        half8 t2 = {bv[0], bv[1], bv[2], bv[3], (_Float16)0.0f, (_Float16)0.0f,
                    (_Float16)0.0f, (_Float16)0.0f};
        b1s = t1;
        b1b = t2;
    }

    f32x16 acc_s = zero16, acc_b = zero16;
    int jw = w * JW;

    // convoy-breaking wave stagger (no sync points in main loop -> persists)
    {
        int ph = w & 3;
        if (ph == 1) __builtin_amdgcn_s_sleep(2);
        else if (ph == 2) __builtin_amdgcn_s_sleep(4);
        else if (ph == 3) __builtin_amdgcn_s_sleep(6);
    }

    // load operands for s-iter K (wrap: harmless L2-hit reload at the tail)
#define LOADOPS(O, K)                                                          \
    {                                                                          \
        int _j0 = jw + ((K) & (NS - 1)) * 32;                                  \
        int _jt = _j0 >> 4;                                                    \
        half4 _avs = *(const half4*)(ajs_c + (size_t)(_j0 + li) * 16 + hs * 8);\
        half4 _avb = *(const half4*)(ajb_c + (size_t)(_j0 + li) * 16 + hs * 8);\
        const _Float16* _p0 = pf_in + (size_t)(_jt * 16 + cr) * 16;            \
        const _Float16* _p1 = pf_in + (size_t)((_jt + 1) * 16 + cr) * 16;      \
        half4 _p0l = *(const half4*)&_p0[4 * hs];                              \
        half4 _p0h = *(const half4*)&_p0[8 + 4 * hs];                          \
        half4 _p1l = *(const half4*)&_p1[4 * hs];                              \
        half4 _p1h = *(const half4*)&_p1[8 + 4 * hs];                          \
        half8 _as = {_avs[0], _avs[1], _avs[2], _avs[3], (_Float16)0.0f,       \
                     (_Float16)0.0f, (_Float16)0.0f, (_Float16)0.0f};          \
        half8 _ab = {_avb[0], _avb[1], _avb[2], _avb[3], (_Float16)0.0f,       \
                     (_Float16)0.0f, (_Float16)0.0f, (_Float16)0.0f};          \
        half8 _a20 = {_p0l[0], _p0l[1], _p0l[2], _p0l[3],                      \
                      _p0h[0], _p0h[1], _p0h[2], _p0h[3]};                     \
        half8 _a21 = {_p1l[0], _p1l[1], _p1l[2], _p1l[3],                      \
                      _p1h[0], _p1h[1], _p1h[2], _p1h[3]};                     \
        O.A_s = _as; O.A_b = _ab; O.A20 = _a20; O.A21 = _a21;                  \
    }
#define G1(DS, DB, O)                                                          \
    {                                                                          \
        DS = __builtin_amdgcn_mfma_f32_32x32x16_f16(O.A_s, b1s, zero16, 0, 0, 0); \
        DB = __builtin_amdgcn_mfma_f32_32x32x16_f16(O.A_b, b1b, zero16, 0, 0, 0); \
    }
    // pkexp(d1) -> B-frags progressively (d halves die as B-frags are built),
    // then G2 accumulate (consumes O's A2 frags)
#define PKG2(DS, DB, O)                                                        \
    {                                                                          \
        half8 _Bs0 = mk8(pkexp(DS[0], DS[1]), pkexp(DS[2], DS[3]),             \
                         pkexp(DS[4], DS[5]), pkexp(DS[6], DS[7]));            \
        half8 _Bs1 = mk8(pkexp(DS[8], DS[9]), pkexp(DS[10], DS[11]),           \
                         pkexp(DS[12], DS[13]), pkexp(DS[14], DS[15]));        \
        __builtin_amdgcn_s_setprio(1);                                         \
        acc_s = __builtin_amdgcn_mfma_f32_32x32x16_f16(O.A20, _Bs0, acc_s, 0, 0, 0); \
        acc_s = __builtin_amdgcn_mfma_f32_32x32x16_f16(O.A21, _Bs1, acc_s, 0, 0, 0); \
        __builtin_amdgcn_s_setprio(0);                                         \
        half8 _Bb0 = mk8(pkexp(DB[0], DB[1]), pkexp(DB[2], DB[3]),             \
                         pkexp(DB[4], DB[5]), pkexp(DB[6], DB[7]));            \
        half8 _Bb1 = mk8(pkexp(DB[8], DB[9]), pkexp(DB[10], DB[11]),           \
                         pkexp(DB[12], DB[13]), pkexp(DB[14], DB[15]));        \
        __builtin_amdgcn_s_setprio(1);                                         \
        acc_b = __builtin_amdgcn_mfma_f32_32x32x16_f16(O.A20, _Bb0, acc_b, 0, 0, 0); \
        acc_b = __builtin_amdgcn_mfma_f32_32x32x16_f16(O.A21, _Bb1, acc_b, 0, 0, 0); \
        __builtin_amdgcn_s_setprio(0);                                         \
    }

    Ops opA, opB;
    f32x16 ds, db;
    LOADOPS(opA, 0);
    for (int m = 0; m < NS / 2; ++m) {
        // s-iter 2m: G1 on pre-loaded opA; issue loads for 2m+1 under PKG2's shadow
        G1(ds, db, opA);
        LOADOPS(opB, 2 * m + 1);
        PKG2(ds, db, opA);
        // s-iter 2m+1: G1 on opB; issue loads for 2m+2 (wraps at tail)
        G1(ds, db, opB);
        LOADOPS(opA, 2 * m + 2);
        PKG2(ds, db, opB);
    }

#undef LOADOPS
#undef G1
#undef PKG2

    // ---- dump valid acc rows to rbuf[w][filter][c][i] (c = (r&3)+8(r>>2)+4hs) ----
    {
        float* rb = rbuf + w * 640;
        if (hs == 0) {
#pragma unroll
            for (int r = 0; r < 4; ++r) {
                rb[r * 32 + li]       = acc_s[r];
                rb[320 + r * 32 + li] = acc_b[r];
            }
            rb[8 * 32 + li] = acc_s[4];
            rb[9 * 32 + li] = acc_s[5];
            rb[320 + 8 * 32 + li] = acc_b[4];
            rb[320 + 9 * 32 + li] = acc_b[5];
        } else {
#pragma unroll
            for (int r = 0; r < 4; ++r) {
                rb[(4 + r) * 32 + li]       = acc_s[r];
                rb[320 + (4 + r) * 32 + li] = acc_b[r];
            }
        }
    }
    __syncthreads();
    if (t < 640) {
        float tot = 0.f;
#pragma unroll
        for (int w2 = 0; w2 < 16; ++w2) tot += rbuf[w2 * 640 + t];
        rbuf[t] = tot;   // slot t read only by thread t (w2=0 term)
    }
    __syncthreads();

    // ---- combine + compatibility + softmax for this block's 32 i's ----
    if (t < IBLK) {
        int i = i0 + t;
        float sp[C], bl[C];
#pragma unroll
        for (int c = 0; c < C; ++c) {
            sp[c] = rbuf[c * 32 + t];
            bl[c] = rbuf[320 + c * 32 + t];
        }
        float msg[C];
#pragma unroll
        for (int c = 0; c < C; ++c) {
            float m = 0.f;
#pragma unroll
            for (int kk = 0; kk < C; ++kk)
                m += SW[c * C + kk] * sp[kk] + BW[c * C + kk] * bl[kk];
            msg[c] = m;
        }
        float qq[C];
#pragma unroll
        for (int c = 0; c < C; ++c) {
            float pw = 0.f;
#pragma unroll
            for (int kk = 0; kk < C; ++kk) pw += CM[c * C + kk] * msg[kk];
            qq[c] = unaries[c * N + i] - pw;
        }
        if (is_last) {
#pragma unroll
            for (int c = 0; c < C; ++c) out[c * N + i] = qq[c];
        } else {
            float m = qq[0];
#pragma unroll
            for (int c = 1; c < C; ++c) m = fmaxf(m, qq[c]);
            float e[C], s = 0.0f;
#pragma unroll
            for (int c = 0; c < C; ++c) {
                e[c] = __builtin_amdgcn_exp2f((qq[c] - m) * LOG2E);
                s += e[c];
            }
            float inv = 1.0f / s;
#pragma unroll
            for (int c = 0; c < C; ++c) pf_out[PFIDX(i, c)] = (_Float16)(e[c] * inv);
        }
    }
}

extern "C" void kernel_launch(void* const* d_in, const int* in_sizes, int n_in,
                              void* d_out, int out_size, void* d_ws, size_t ws_size,
                              hipStream_t stream) {
    const float* unaries = (const float*)d_in[0];   // [10, 8192]
    const float* feat    = (const float*)d_in[1];   // [6, 8192]
    const float* SW      = (const float*)d_in[2];   // [10,10]
    const float* BW      = (const float*)d_in[3];   // [10,10]
    const float* CM      = (const float*)d_in[4];   // [10,10]
    float* out = (float*)d_out;

    char* ws = (char*)d_ws;
    half8* ajs    = (half8*)(ws + WS_AJS);
    half8* ajb    = (half8*)(ws + WS_AJB);
    _Float16* pf0 = (_Float16*)(ws + WS_PF0);
    _Float16* pf1 = (_Float16*)(ws + WS_PF1);

    init_kernel<<<N / 256, 256, 0, stream>>>(unaries, feat, ajs, ajb, pf0, pf1);
    const _Float16* pin = pf0;
    _Float16* pout = pf1;
    for (int it = 1; it <= NUM_ITERS; ++it) {
        fused_kernel<<<NBLK, FBLOCK, 0, stream>>>(
            unaries, feat, SW, BW, CM, (const char*)ajs, (const char*)ajb,
            pin, pout, out, it == NUM_ITERS ? 1 : 0);
        const _Float16* tmp = pout;
        pout = (_Float16*)pin;
        pin = tmp;
    }
}

// Round 21
// 152.723 us; speedup vs baseline: 2.0375x; 1.0218x over previous
//
#include <hip/hip_runtime.h>
#include <math.h>

#define N 8192
#define C 10
#define NUM_ITERS 5
#define FBLOCK 1024        /* 16 waves, 1 block/CU, 4 waves/SIMD */
#define IBLK 32            /* i's per block */
#define NBLK (N / IBLK)    /* 256 blocks = 1 per CU */
#define JW (N / 16)        /* 512 j's per wave */
#define NS (JW / 32)       /* 16 s-iters per wave, 32 j's each */
#define LOG2E 1.44269504088896340736f
#define C3 (LOG2E / 64.0f)

typedef _Float16 half8 __attribute__((ext_vector_type(8)));
typedef _Float16 half4 __attribute__((ext_vector_type(4)));
typedef _Float16 half2 __attribute__((ext_vector_type(2)));
typedef float f32x4 __attribute__((ext_vector_type(4)));
typedef float f32x16 __attribute__((ext_vector_type(16)));
typedef unsigned int uint4v __attribute__((ext_vector_type(4)));

// ws layout:
//   ajc half8[2*N] 256KB : interleaved j-side aug, per j 32B =
//                          [s(0..3) | b(0..3) | s(4..7) | b(4..7)]
//   pf0/pf1 f16[N/16][16][16] : probs, J-TILED with j-within-tile PERMUTED by
//                               swap23 (bits 2<->3) so G2 A-frags are contiguous
#define WS_AJC 0
#define WS_PF0 (N * 32)
#define WS_PF1 (N * 64)
// permuted position of j within its 16-tile: swap bits 2 and 3
#define SW23(x) (((x) & 3) | (((x) >> 1) & 4) | (((x) << 1) & 8))
#define PFIDX(n, c) ((((n) >> 4) * 16 + (c)) * 16 + SW23((n) & 15))

static __device__ __forceinline__ unsigned int pkexp(float a, float b) {
    float ea = __builtin_amdgcn_exp2f(a);
    float eb = __builtin_amdgcn_exp2f(b);
    return __builtin_bit_cast(unsigned int, __builtin_amdgcn_cvt_pkrtz(ea, eb));
}

static __device__ __forceinline__ half8 mk8(unsigned int a, unsigned int b,
                                            unsigned int c, unsigned int d) {
    uint4v v = {a, b, c, d};
    return __builtin_bit_cast(half8, v);
}

// once per launch: interleaved aug features + softmax(unaries) -> pf0 (permuted
// tiles); zero rows 10..15 of both pf
__global__ __launch_bounds__(256) void init_kernel(
    const float* __restrict__ unaries, const float* __restrict__ feat,
    half8* __restrict__ ajc, _Float16* __restrict__ pf0,
    _Float16* __restrict__ pf1) {
    int n = blockIdx.x * 256 + threadIdx.x;
    float f6[6];
#pragma unroll
    for (int d = 0; d < 6; ++d) f6[d] = feat[d * N + n];
    float h3 = 0.5f * (f6[0] * f6[0] + f6[1] * f6[1] + f6[2] * f6[2]);
    float h6v = h3 + 0.5f * (f6[3] * f6[3] + f6[4] * f6[4] + f6[5] * f6[5]);
    // s = [f0*C3, f1*C3, f2*C3, 0, 0, 0, -h3*C3, 1] ; b = [f*L2E x6, -h6*L2E, 1]
    half8 lo = {(_Float16)(f6[0] * C3), (_Float16)(f6[1] * C3),
                (_Float16)(f6[2] * C3), (_Float16)0.0f,
                (_Float16)(f6[0] * LOG2E), (_Float16)(f6[1] * LOG2E),
                (_Float16)(f6[2] * LOG2E), (_Float16)(f6[3] * LOG2E)};
    half8 hi = {(_Float16)0.0f, (_Float16)0.0f, (_Float16)(-h3 * C3),
                (_Float16)1.0f,
                (_Float16)(f6[4] * LOG2E), (_Float16)(f6[5] * LOG2E),
                (_Float16)(-h6v * LOG2E), (_Float16)1.0f};
    ajc[n * 2] = lo;
    ajc[n * 2 + 1] = hi;

    float q[C];
#pragma unroll
    for (int c = 0; c < C; ++c) q[c] = unaries[c * N + n];
    float m = q[0];
#pragma unroll
    for (int c = 1; c < C; ++c) m = fmaxf(m, q[c]);
    float e[C], s = 0.0f;
#pragma unroll
    for (int c = 0; c < C; ++c) {
        e[c] = __builtin_amdgcn_exp2f((q[c] - m) * LOG2E);
        s += e[c];
    }
    float inv = 1.0f / s;
#pragma unroll
    for (int c = 0; c < C; ++c) pf0[PFIDX(n, c)] = (_Float16)(e[c] * inv);
#pragma unroll
    for (int c = C; c < 16; ++c) {
        pf0[PFIDX(n, c)] = (_Float16)0.0f;
        pf1[PFIDX(n, c)] = (_Float16)0.0f;
    }
}

// operand bundle for one s-iter (named members only -> registers)
struct Ops { half8 A_s, A_b, A20, A21; };

// one dispatch per CRF iteration. Register-only main loop (R17 math, verified),
// load-prefetch 1 s-iter deep (R19, +6us), now with 3 vector loads per s-iter:
// 1x16B interleaved aj (both filters) + 2x16B permuted-pf A-frags.
__global__ __launch_bounds__(FBLOCK, 4) void fused_kernel(
    const float* __restrict__ unaries, const float* __restrict__ feat,
    const float* __restrict__ SW, const float* __restrict__ BW,
    const float* __restrict__ CM, const half8* __restrict__ ajc,
    const _Float16* __restrict__ pf_in, _Float16* __restrict__ pf_out,
    float* __restrict__ out, int is_last) {
    __shared__ float rbuf[16 * 640];   // 40 KB, epilogue only
    int t = threadIdx.x;
    int i0 = blockIdx.x * IBLK;
    int lane = t & 63;
    int w = t >> 6;
    int li = lane & 31;      // i (G1/G2 D col) or j (G1 A row) within 32
    int hs = lane >> 5;      // K-half select
    int cr = li & 15;        // p-row for G2 A-operand (c-rows 16..31 discarded)
    const f32x16 zero16 = {};

    // ---- B1 fragments (G1 B-operand): lane holds aug[4hs..4hs+3] of i=i0+li ----
    half8 b1s, b1b;
    {
        int i = i0 + li;
        float g0 = feat[0 * N + i], g1 = feat[1 * N + i], g2 = feat[2 * N + i];
        float g3 = feat[3 * N + i], g4 = feat[4 * N + i], g5 = feat[5 * N + i];
        float h3 = 0.5f * (g0 * g0 + g1 * g1 + g2 * g2);
        float h6v = h3 + 0.5f * (g3 * g3 + g4 * g4 + g5 * g5);
        half4 slo = {(_Float16)g0, (_Float16)g1, (_Float16)g2, (_Float16)0.0f};
        half4 shi = {(_Float16)0.0f, (_Float16)0.0f, (_Float16)1.0f, (_Float16)(-h3 * C3)};
        half4 blo = {(_Float16)g0, (_Float16)g1, (_Float16)g2, (_Float16)g3};
        half4 bhi = {(_Float16)g4, (_Float16)g5, (_Float16)1.0f, (_Float16)(-h6v * LOG2E)};
        half4 sv = hs ? shi : slo;
        half4 bv = hs ? bhi : blo;
        half8 t1 = {sv[0], sv[1], sv[2], sv[3], (_Float16)0.0f, (_Float16)0.0f,
                    (_Float16)0.0f, (_Float16)0.0f};
        half8 t2 = {bv[0], bv[1], bv[2], bv[3], (_Float16)0.0f, (_Float16)0.0f,
                    (_Float16)0.0f, (_Float16)0.0f};
        // NOTE: b1 uses UNscaled g0..g2 for the spatial low half -- matches the
        // original formulation: scaling by C3 lives on the j-side (A operand).
        b1s = t1;
        b1b = t2;
    }

    f32x16 acc_s = zero16, acc_b = zero16;
    int jw = w * JW;

    // convoy-breaking wave stagger (no sync points in main loop -> persists)
    {
        int ph = w & 3;
        if (ph == 1) __builtin_amdgcn_s_sleep(2);
        else if (ph == 2) __builtin_amdgcn_s_sleep(4);
        else if (ph == 3) __builtin_amdgcn_s_sleep(6);
    }

    // load operands for s-iter K: 3 x 16B vector loads
#define LOADOPS(O, K)                                                          \
    {                                                                          \
        int _j0 = jw + ((K) & (NS - 1)) * 32;                                  \
        int _jt = _j0 >> 4;                                                    \
        half8 _av = ajc[(size_t)(_j0 + li) * 2 + hs];                          \
        half8 _a20 = *(const half8*)&pf_in[(size_t)(_jt * 16 + cr) * 16 + 8 * hs]; \
        half8 _a21 = *(const half8*)&pf_in[(size_t)((_jt + 1) * 16 + cr) * 16 + 8 * hs]; \
        half8 _as = {_av[0], _av[1], _av[2], _av[3], (_Float16)0.0f,           \
                     (_Float16)0.0f, (_Float16)0.0f, (_Float16)0.0f};          \
        half8 _ab = {_av[4], _av[5], _av[6], _av[7], (_Float16)0.0f,           \
                     (_Float16)0.0f, (_Float16)0.0f, (_Float16)0.0f};          \
        O.A_s = _as; O.A_b = _ab; O.A20 = _a20; O.A21 = _a21;                  \
    }
#define G1(DS, DB, O)                                                          \
    {                                                                          \
        DS = __builtin_amdgcn_mfma_f32_32x32x16_f16(O.A_s, b1s, zero16, 0, 0, 0); \
        DB = __builtin_amdgcn_mfma_f32_32x32x16_f16(O.A_b, b1b, zero16, 0, 0, 0); \
    }
    // pkexp -> B-frags; G2 interleaved s,b,s,b (two serial acc chains overlap)
#define PKG2(DS, DB, O)                                                        \
    {                                                                          \
        half8 _Bs0 = mk8(pkexp(DS[0], DS[1]), pkexp(DS[2], DS[3]),             \
                         pkexp(DS[4], DS[5]), pkexp(DS[6], DS[7]));            \
        half8 _Bb0 = mk8(pkexp(DB[0], DB[1]), pkexp(DB[2], DB[3]),             \
                         pkexp(DB[4], DB[5]), pkexp(DB[6], DB[7]));            \
        half8 _Bs1 = mk8(pkexp(DS[8], DS[9]), pkexp(DS[10], DS[11]),           \
                         pkexp(DS[12], DS[13]), pkexp(DS[14], DS[15]));        \
        half8 _Bb1 = mk8(pkexp(DB[8], DB[9]), pkexp(DB[10], DB[11]),           \
                         pkexp(DB[12], DB[13]), pkexp(DB[14], DB[15]));        \
        __builtin_amdgcn_s_setprio(1);                                         \
        acc_s = __builtin_amdgcn_mfma_f32_32x32x16_f16(O.A20, _Bs0, acc_s, 0, 0, 0); \
        acc_b = __builtin_amdgcn_mfma_f32_32x32x16_f16(O.A20, _Bb0, acc_b, 0, 0, 0); \
        acc_s = __builtin_amdgcn_mfma_f32_32x32x16_f16(O.A21, _Bs1, acc_s, 0, 0, 0); \
        acc_b = __builtin_amdgcn_mfma_f32_32x32x16_f16(O.A21, _Bb1, acc_b, 0, 0, 0); \
        __builtin_amdgcn_s_setprio(0);                                         \
    }

    Ops opA, opB;
    f32x16 ds, db;
    LOADOPS(opA, 0);
    for (int m = 0; m < NS / 2; ++m) {
        // s-iter 2m: G1 on pre-loaded opA; issue loads for 2m+1 under PKG2's shadow
        G1(ds, db, opA);
        LOADOPS(opB, 2 * m + 1);
        PKG2(ds, db, opA);
        // s-iter 2m+1: G1 on opB; issue loads for 2m+2 (wraps at tail)
        G1(ds, db, opB);
        LOADOPS(opA, 2 * m + 2);
        PKG2(ds, db, opB);
    }

#undef LOADOPS
#undef G1
#undef PKG2

    // ---- dump valid acc rows to rbuf[w][filter][c][i] (c = (r&3)+8(r>>2)+4hs) ----
    {
        float* rb = rbuf + w * 640;
        if (hs == 0) {
#pragma unroll
            for (int r = 0; r < 4; ++r) {
                rb[r * 32 + li]       = acc_s[r];
                rb[320 + r * 32 + li] = acc_b[r];
            }
            rb[8 * 32 + li] = acc_s[4];
            rb[9 * 32 + li] = acc_s[5];
            rb[320 + 8 * 32 + li] = acc_b[4];
            rb[320 + 9 * 32 + li] = acc_b[5];
        } else {
#pragma unroll
            for (int r = 0; r < 4; ++r) {
                rb[(4 + r) * 32 + li]       = acc_s[r];
                rb[320 + (4 + r) * 32 + li] = acc_b[r];
            }
        }
    }
    __syncthreads();
    if (t < 640) {
        float tot = 0.f;
#pragma unroll
        for (int w2 = 0; w2 < 16; ++w2) tot += rbuf[w2 * 640 + t];
        rbuf[t] = tot;   // slot t read only by thread t (w2=0 term)
    }
    __syncthreads();

    // ---- combine + compatibility + softmax for this block's 32 i's ----
    if (t < IBLK) {
        int i = i0 + t;
        float sp[C], bl[C];
#pragma unroll
        for (int c = 0; c < C; ++c) {
            sp[c] = rbuf[c * 32 + t];
            bl[c] = rbuf[320 + c * 32 + t];
        }
        float msg[C];
#pragma unroll
        for (int c = 0; c < C; ++c) {
            float m = 0.f;
#pragma unroll
            for (int kk = 0; kk < C; ++kk)
                m += SW[c * C + kk] * sp[kk] + BW[c * C + kk] * bl[kk];
            msg[c] = m;
        }
        float qq[C];
#pragma unroll
        for (int c = 0; c < C; ++c) {
            float pw = 0.f;
#pragma unroll
            for (int kk = 0; kk < C; ++kk) pw += CM[c * C + kk] * msg[kk];
            qq[c] = unaries[c * N + i] - pw;
        }
        if (is_last) {
#pragma unroll
            for (int c = 0; c < C; ++c) out[c * N + i] = qq[c];
        } else {
            float m = qq[0];
#pragma unroll
            for (int c = 1; c < C; ++c) m = fmaxf(m, qq[c]);
            float e[C], s = 0.0f;
#pragma unroll
            for (int c = 0; c < C; ++c) {
                e[c] = __builtin_amdgcn_exp2f((qq[c] - m) * LOG2E);
                s += e[c];
            }
            float inv = 1.0f / s;
#pragma unroll
            for (int c = 0; c < C; ++c) pf_out[PFIDX(i, c)] = (_Float16)(e[c] * inv);
        }
    }
}

extern "C" void kernel_launch(void* const* d_in, const int* in_sizes, int n_in,
                              void* d_out, int out_size, void* d_ws, size_t ws_size,
                              hipStream_t stream) {
    const float* unaries = (const float*)d_in[0];   // [10, 8192]
    const float* feat    = (const float*)d_in[1];   // [6, 8192]
    const float* SW      = (const float*)d_in[2];   // [10,10]
    const float* BW      = (const float*)d_in[3];   // [10,10]
    const float* CM      = (const float*)d_in[4];   // [10,10]
    float* out = (float*)d_out;

    char* ws = (char*)d_ws;
    half8* ajc    = (half8*)(ws + WS_AJC);
    _Float16* pf0 = (_Float16*)(ws + WS_PF0);
    _Float16* pf1 = (_Float16*)(ws + WS_PF1);

    init_kernel<<<N / 256, 256, 0, stream>>>(unaries, feat, ajc, pf0, pf1);
    const _Float16* pin = pf0;
    _Float16* pout = pf1;
    for (int it = 1; it <= NUM_ITERS; ++it) {
        fused_kernel<<<NBLK, FBLOCK, 0, stream>>>(
            unaries, feat, SW, BW, CM, ajc, pin, pout, out,
            it == NUM_ITERS ? 1 : 0);
        const _Float16* tmp = pout;
        pout = (_Float16*)pin;
        pin = tmp;
    }
}

// Round 22
// 150.251 us; speedup vs baseline: 2.0710x; 1.0165x over previous
//
#include <hip/hip_runtime.h>
#include <math.h>

#define N 8192
#define C 10
#define NUM_ITERS 5
#define FBLOCK 1024        /* 16 waves, 1 block/CU, 4 waves/SIMD */
#define IBLK 32            /* i's per block */
#define NBLK (N / IBLK)    /* 256 blocks = 1 per CU */
#define JW (N / 16)        /* 512 j's per wave */
#define NS (JW / 32)       /* 16 s-iters per wave, 32 j's each */
#define LOG2E 1.44269504088896340736f
#define C3 (LOG2E / 64.0f)

typedef _Float16 half8 __attribute__((ext_vector_type(8)));
typedef _Float16 half4 __attribute__((ext_vector_type(4)));
typedef _Float16 half2 __attribute__((ext_vector_type(2)));
typedef float f32x4 __attribute__((ext_vector_type(4)));
typedef float f32x16 __attribute__((ext_vector_type(16)));
typedef unsigned int uint4v __attribute__((ext_vector_type(4)));

// ws layout:
//   ajc half8[2*N] 256KB : interleaved j-side aug, per j 32B =
//                          [s(0..3) | b(0..3) | s(4..7) | b(4..7)]
//   pf0/pf1 f16[N/16][16][16] : probs, J-TILED with j-within-tile PERMUTED by
//                               swap23 (bits 2<->3) so G2 A-frags are contiguous
#define WS_AJC 0
#define WS_PF0 (N * 32)
#define WS_PF1 (N * 64)
// permuted position of j within its 16-tile: swap bits 2 and 3
#define SW23(x) (((x) & 3) | (((x) >> 1) & 4) | (((x) << 1) & 8))
#define PFIDX(n, c) ((((n) >> 4) * 16 + (c)) * 16 + SW23((n) & 15))

static __device__ __forceinline__ unsigned int pkexp(float a, float b) {
    float ea = __builtin_amdgcn_exp2f(a);
    float eb = __builtin_amdgcn_exp2f(b);
    return __builtin_bit_cast(unsigned int, __builtin_amdgcn_cvt_pkrtz(ea, eb));
}

static __device__ __forceinline__ half8 mk8(unsigned int a, unsigned int b,
                                            unsigned int c, unsigned int d) {
    uint4v v = {a, b, c, d};
    return __builtin_bit_cast(half8, v);
}

// once per launch: interleaved aug features + softmax(unaries) -> pf0 (permuted
// tiles); zero rows 10..15 of both pf
__global__ __launch_bounds__(256) void init_kernel(
    const float* __restrict__ unaries, const float* __restrict__ feat,
    half8* __restrict__ ajc, _Float16* __restrict__ pf0,
    _Float16* __restrict__ pf1) {
    int n = blockIdx.x * 256 + threadIdx.x;
    float f6[6];
#pragma unroll
    for (int d = 0; d < 6; ++d) f6[d] = feat[d * N + n];
    float h3 = 0.5f * (f6[0] * f6[0] + f6[1] * f6[1] + f6[2] * f6[2]);
    float h6v = h3 + 0.5f * (f6[3] * f6[3] + f6[4] * f6[4] + f6[5] * f6[5]);
    // s = [f0*C3, f1*C3, f2*C3, 0, 0, 0, -h3*C3, 1] ; b = [f*L2E x6, -h6*L2E, 1]
    half8 lo = {(_Float16)(f6[0] * C3), (_Float16)(f6[1] * C3),
                (_Float16)(f6[2] * C3), (_Float16)0.0f,
                (_Float16)(f6[0] * LOG2E), (_Float16)(f6[1] * LOG2E),
                (_Float16)(f6[2] * LOG2E), (_Float16)(f6[3] * LOG2E)};
    half8 hi = {(_Float16)0.0f, (_Float16)0.0f, (_Float16)(-h3 * C3),
                (_Float16)1.0f,
                (_Float16)(f6[4] * LOG2E), (_Float16)(f6[5] * LOG2E),
                (_Float16)(-h6v * LOG2E), (_Float16)1.0f};
    ajc[n * 2] = lo;
    ajc[n * 2 + 1] = hi;

    float q[C];
#pragma unroll
    for (int c = 0; c < C; ++c) q[c] = unaries[c * N + n];
    float m = q[0];
#pragma unroll
    for (int c = 1; c < C; ++c) m = fmaxf(m, q[c]);
    float e[C], s = 0.0f;
#pragma unroll
    for (int c = 0; c < C; ++c) {
        e[c] = __builtin_amdgcn_exp2f((q[c] - m) * LOG2E);
        s += e[c];
    }
    float inv = 1.0f / s;
#pragma unroll
    for (int c = 0; c < C; ++c) pf0[PFIDX(n, c)] = (_Float16)(e[c] * inv);
#pragma unroll
    for (int c = C; c < 16; ++c) {
        pf0[PFIDX(n, c)] = (_Float16)0.0f;
        pf1[PFIDX(n, c)] = (_Float16)0.0f;
    }
}

// operand bundle for one s-iter (named members only -> registers)
struct Ops { half8 Av, A20, A21; };

// one dispatch per CRF iteration. Register-only main loop, load-prefetch 1 deep,
// 3x16B loads/s-iter. NEW vs R21: SHARED-A GEMM-1 -- the raw interleaved ajc
// load feeds BOTH filters' G1 directly (b1s zeros kill the b-quad, b1b's values
// live in the TOP half so its zeros kill the s-quad). Zero A-assembly VALU.
__global__ __launch_bounds__(FBLOCK, 4) void fused_kernel(
    const float* __restrict__ unaries, const float* __restrict__ feat,
    const float* __restrict__ SW, const float* __restrict__ BW,
    const float* __restrict__ CM, const half8* __restrict__ ajc,
    const _Float16* __restrict__ pf_in, _Float16* __restrict__ pf_out,
    float* __restrict__ out, int is_last) {
    __shared__ float rbuf[16 * 640];   // 40 KB, epilogue only
    int t = threadIdx.x;
    int i0 = blockIdx.x * IBLK;
    int lane = t & 63;
    int w = t >> 6;
    int li = lane & 31;      // i (G1/G2 D col) or j (G1 A row) within 32
    int hs = lane >> 5;      // K-half select
    int cr = li & 15;        // p-row for G2 A-operand (c-rows 16..31 discarded)
    const f32x16 zero16 = {};

    // ---- B1 fragments: b1s = {s-aug quad, 0x4}; b1b = {0x4, b-aug quad} ----
    half8 b1s, b1b;
    {
        int i = i0 + li;
        float g0 = feat[0 * N + i], g1 = feat[1 * N + i], g2 = feat[2 * N + i];
        float g3 = feat[3 * N + i], g4 = feat[4 * N + i], g5 = feat[5 * N + i];
        float h3 = 0.5f * (g0 * g0 + g1 * g1 + g2 * g2);
        float h6v = h3 + 0.5f * (g3 * g3 + g4 * g4 + g5 * g5);
        half4 slo = {(_Float16)g0, (_Float16)g1, (_Float16)g2, (_Float16)0.0f};
        half4 shi = {(_Float16)0.0f, (_Float16)0.0f, (_Float16)1.0f, (_Float16)(-h3 * C3)};
        half4 blo = {(_Float16)g0, (_Float16)g1, (_Float16)g2, (_Float16)g3};
        half4 bhi = {(_Float16)g4, (_Float16)g5, (_Float16)1.0f, (_Float16)(-h6v * LOG2E)};
        half4 sv = hs ? shi : slo;
        half4 bv = hs ? bhi : blo;
        half8 t1 = {sv[0], sv[1], sv[2], sv[3], (_Float16)0.0f, (_Float16)0.0f,
                    (_Float16)0.0f, (_Float16)0.0f};
        half8 t2 = {(_Float16)0.0f, (_Float16)0.0f, (_Float16)0.0f,
                    (_Float16)0.0f, bv[0], bv[1], bv[2], bv[3]};
        b1s = t1;
        b1b = t2;
    }

    f32x16 acc_s = zero16, acc_b = zero16;
    int jw = w * JW;

    // convoy-breaking wave stagger (no sync points in main loop -> persists)
    {
        int ph = w & 3;
        if (ph == 1) __builtin_amdgcn_s_sleep(2);
        else if (ph == 2) __builtin_amdgcn_s_sleep(4);
        else if (ph == 3) __builtin_amdgcn_s_sleep(6);
    }

    // load operands for s-iter K: 3 x 16B vector loads, zero unpack VALU
#define LOADOPS(O, K)                                                          \
    {                                                                          \
        int _j0 = jw + ((K) & (NS - 1)) * 32;                                  \
        int _jt = _j0 >> 4;                                                    \
        O.Av = ajc[(size_t)(_j0 + li) * 2 + hs];                               \
        O.A20 = *(const half8*)&pf_in[(size_t)(_jt * 16 + cr) * 16 + 8 * hs];  \
        O.A21 = *(const half8*)&pf_in[(size_t)((_jt + 1) * 16 + cr) * 16 + 8 * hs]; \
    }
    // shared-A G1: garbage quads are annihilated by B1's zero halves
#define G1(DS, DB, O)                                                          \
    {                                                                          \
        DS = __builtin_amdgcn_mfma_f32_32x32x16_f16(O.Av, b1s, zero16, 0, 0, 0); \
        DB = __builtin_amdgcn_mfma_f32_32x32x16_f16(O.Av, b1b, zero16, 0, 0, 0); \
    }
    // pkexp -> B-frags; G2 interleaved s,b,s,b (two serial acc chains overlap)
#define PKG2(DS, DB, O)                                                        \
    {                                                                          \
        half8 _Bs0 = mk8(pkexp(DS[0], DS[1]), pkexp(DS[2], DS[3]),             \
                         pkexp(DS[4], DS[5]), pkexp(DS[6], DS[7]));            \
        half8 _Bb0 = mk8(pkexp(DB[0], DB[1]), pkexp(DB[2], DB[3]),             \
                         pkexp(DB[4], DB[5]), pkexp(DB[6], DB[7]));            \
        half8 _Bs1 = mk8(pkexp(DS[8], DS[9]), pkexp(DS[10], DS[11]),           \
                         pkexp(DS[12], DS[13]), pkexp(DS[14], DS[15]));        \
        half8 _Bb1 = mk8(pkexp(DB[8], DB[9]), pkexp(DB[10], DB[11]),           \
                         pkexp(DB[12], DB[13]), pkexp(DB[14], DB[15]));        \
        __builtin_amdgcn_s_setprio(1);                                         \
        acc_s = __builtin_amdgcn_mfma_f32_32x32x16_f16(O.A20, _Bs0, acc_s, 0, 0, 0); \
        acc_b = __builtin_amdgcn_mfma_f32_32x32x16_f16(O.A20, _Bb0, acc_b, 0, 0, 0); \
        acc_s = __builtin_amdgcn_mfma_f32_32x32x16_f16(O.A21, _Bs1, acc_s, 0, 0, 0); \
        acc_b = __builtin_amdgcn_mfma_f32_32x32x16_f16(O.A21, _Bb1, acc_b, 0, 0, 0); \
        __builtin_amdgcn_s_setprio(0);                                         \
    }

    Ops opA, opB;
    f32x16 ds, db;
    LOADOPS(opA, 0);
    for (int m = 0; m < NS / 2; ++m) {
        // s-iter 2m: G1 on pre-loaded opA; issue loads for 2m+1 under PKG2's shadow
        G1(ds, db, opA);
        LOADOPS(opB, 2 * m + 1);
        PKG2(ds, db, opA);
        // s-iter 2m+1: G1 on opB; issue loads for 2m+2 (wraps at tail)
        G1(ds, db, opB);
        LOADOPS(opA, 2 * m + 2);
        PKG2(ds, db, opB);
    }

#undef LOADOPS
#undef G1
#undef PKG2

    // ---- dump valid acc rows to rbuf[w][filter][c][i] (c = (r&3)+8(r>>2)+4hs) ----
    {
        float* rb = rbuf + w * 640;
        if (hs == 0) {
#pragma unroll
            for (int r = 0; r < 4; ++r) {
                rb[r * 32 + li]       = acc_s[r];
                rb[320 + r * 32 + li] = acc_b[r];
            }
            rb[8 * 32 + li] = acc_s[4];
            rb[9 * 32 + li] = acc_s[5];
            rb[320 + 8 * 32 + li] = acc_b[4];
            rb[320 + 9 * 32 + li] = acc_b[5];
        } else {
#pragma unroll
            for (int r = 0; r < 4; ++r) {
                rb[(4 + r) * 32 + li]       = acc_s[r];
                rb[320 + (4 + r) * 32 + li] = acc_b[r];
            }
        }
    }
    __syncthreads();
    if (t < 640) {
        float tot = 0.f;
#pragma unroll
        for (int w2 = 0; w2 < 16; ++w2) tot += rbuf[w2 * 640 + t];
        rbuf[t] = tot;   // slot t read only by thread t (w2=0 term)
    }
    __syncthreads();

    // ---- combine + compatibility + softmax for this block's 32 i's ----
    if (t < IBLK) {
        int i = i0 + t;
        float sp[C], bl[C];
#pragma unroll
        for (int c = 0; c < C; ++c) {
            sp[c] = rbuf[c * 32 + t];
            bl[c] = rbuf[320 + c * 32 + t];
        }
        float msg[C];
#pragma unroll
        for (int c = 0; c < C; ++c) {
            float m = 0.f;
#pragma unroll
            for (int kk = 0; kk < C; ++kk)
                m += SW[c * C + kk] * sp[kk] + BW[c * C + kk] * bl[kk];
            msg[c] = m;
        }
        float qq[C];
#pragma unroll
        for (int c = 0; c < C; ++c) {
            float pw = 0.f;
#pragma unroll
            for (int kk = 0; kk < C; ++kk) pw += CM[c * C + kk] * msg[kk];
            qq[c] = unaries[c * N + i] - pw;
        }
        if (is_last) {
#pragma unroll
            for (int c = 0; c < C; ++c) out[c * N + i] = qq[c];
        } else {
            float m = qq[0];
#pragma unroll
            for (int c = 1; c < C; ++c) m = fmaxf(m, qq[c]);
            float e[C], s = 0.0f;
#pragma unroll
            for (int c = 0; c < C; ++c) {
                e[c] = __builtin_amdgcn_exp2f((qq[c] - m) * LOG2E);
                s += e[c];
            }
            float inv = 1.0f / s;
#pragma unroll
            for (int c = 0; c < C; ++c) pf_out[PFIDX(i, c)] = (_Float16)(e[c] * inv);
        }
    }
}

extern "C" void kernel_launch(void* const* d_in, const int* in_sizes, int n_in,
                              void* d_out, int out_size, void* d_ws, size_t ws_size,
                              hipStream_t stream) {
    const float* unaries = (const float*)d_in[0];   // [10, 8192]
    const float* feat    = (const float*)d_in[1];   // [6, 8192]
    const float* SW      = (const float*)d_in[2];   // [10,10]
    const float* BW      = (const float*)d_in[3];   // [10,10]
    const float* CM      = (const float*)d_in[4];   // [10,10]
    float* out = (float*)d_out;

    char* ws = (char*)d_ws;
    half8* ajc    = (half8*)(ws + WS_AJC);
    _Float16* pf0 = (_Float16*)(ws + WS_PF0);
    _Float16* pf1 = (_Float16*)(ws + WS_PF1);

    init_kernel<<<N / 256, 256, 0, stream>>>(unaries, feat, ajc, pf0, pf1);
    const _Float16* pin = pf0;
    _Float16* pout = pf1;
    for (int it = 1; it <= NUM_ITERS; ++it) {
        fused_kernel<<<NBLK, FBLOCK, 0, stream>>>(
            unaries, feat, SW, BW, CM, ajc, pin, pout, out,
            it == NUM_ITERS ? 1 : 0);
        const _Float16* tmp = pout;
        pout = (_Float16*)pin;
        pin = tmp;
    }
}

// Round 23
// 150.050 us; speedup vs baseline: 2.0738x; 1.0013x over previous
//
#include <hip/hip_runtime.h>
#include <math.h>

#define N 8192
#define C 10
#define NUM_ITERS 5
#define FBLOCK 1024        /* 16 waves, 1 block/CU, 4 waves/SIMD */
#define IBLK 32            /* i's per block */
#define NBLK (N / IBLK)    /* 256 blocks = 1 per CU */
#define JW (N / 16)        /* 512 j's per wave */
#define NS (JW / 32)       /* 16 s-iters per wave, 32 j's each */
#define LOG2E 1.44269504088896340736f
#define C3 (LOG2E / 64.0f)

typedef _Float16 half8 __attribute__((ext_vector_type(8)));
typedef _Float16 half4 __attribute__((ext_vector_type(4)));
typedef _Float16 half2 __attribute__((ext_vector_type(2)));
typedef float f32x4 __attribute__((ext_vector_type(4)));
typedef float f32x16 __attribute__((ext_vector_type(16)));
typedef unsigned int uint4v __attribute__((ext_vector_type(4)));

// ws layout:
//   ajc half8[2*N] 256KB : interleaved j-side aug, per j 32B =
//                          [s(0..3) | b(0..3) | s(4..7) | b(4..7)]
//   pf0/pf1 f16[N/16][16][16] : probs, J-TILED with j-within-tile PERMUTED by
//                               swap23 (bits 2<->3) so G2 A-frags are contiguous
#define WS_AJC 0
#define WS_PF0 (N * 32)
#define WS_PF1 (N * 64)
// permuted position of j within its 16-tile: swap bits 2 and 3
#define SW23(x) (((x) & 3) | (((x) >> 1) & 4) | (((x) << 1) & 8))
#define PFIDX(n, c) ((((n) >> 4) * 16 + (c)) * 16 + SW23((n) & 15))

static __device__ __forceinline__ unsigned int pkexp(float a, float b) {
    float ea = __builtin_amdgcn_exp2f(a);
    float eb = __builtin_amdgcn_exp2f(b);
    return __builtin_bit_cast(unsigned int, __builtin_amdgcn_cvt_pkrtz(ea, eb));
}

static __device__ __forceinline__ half8 mk8(unsigned int a, unsigned int b,
                                            unsigned int c, unsigned int d) {
    uint4v v = {a, b, c, d};
    return __builtin_bit_cast(half8, v);
}

// once per launch: interleaved aug features + softmax(unaries) -> pf0 (permuted
// tiles); zero rows 10..15 of both pf
__global__ __launch_bounds__(256) void init_kernel(
    const float* __restrict__ unaries, const float* __restrict__ feat,
    half8* __restrict__ ajc, _Float16* __restrict__ pf0,
    _Float16* __restrict__ pf1) {
    int n = blockIdx.x * 256 + threadIdx.x;
    float f6[6];
#pragma unroll
    for (int d = 0; d < 6; ++d) f6[d] = feat[d * N + n];
    float h3 = 0.5f * (f6[0] * f6[0] + f6[1] * f6[1] + f6[2] * f6[2]);
    float h6v = h3 + 0.5f * (f6[3] * f6[3] + f6[4] * f6[4] + f6[5] * f6[5]);
    half8 lo = {(_Float16)(f6[0] * C3), (_Float16)(f6[1] * C3),
                (_Float16)(f6[2] * C3), (_Float16)0.0f,
                (_Float16)(f6[0] * LOG2E), (_Float16)(f6[1] * LOG2E),
                (_Float16)(f6[2] * LOG2E), (_Float16)(f6[3] * LOG2E)};
    half8 hi = {(_Float16)0.0f, (_Float16)0.0f, (_Float16)(-h3 * C3),
                (_Float16)1.0f,
                (_Float16)(f6[4] * LOG2E), (_Float16)(f6[5] * LOG2E),
                (_Float16)(-h6v * LOG2E), (_Float16)1.0f};
    ajc[n * 2] = lo;
    ajc[n * 2 + 1] = hi;

    float q[C];
#pragma unroll
    for (int c = 0; c < C; ++c) q[c] = unaries[c * N + n];
    float m = q[0];
#pragma unroll
    for (int c = 1; c < C; ++c) m = fmaxf(m, q[c]);
    float e[C], s = 0.0f;
#pragma unroll
    for (int c = 0; c < C; ++c) {
        e[c] = __builtin_amdgcn_exp2f((q[c] - m) * LOG2E);
        s += e[c];
    }
    float inv = 1.0f / s;
#pragma unroll
    for (int c = 0; c < C; ++c) pf0[PFIDX(n, c)] = (_Float16)(e[c] * inv);
#pragma unroll
    for (int c = C; c < 16; ++c) {
        pf0[PFIDX(n, c)] = (_Float16)0.0f;
        pf1[PFIDX(n, c)] = (_Float16)0.0f;
    }
}

// operand bundle for one s-iter (named members only -> registers)
struct Ops { half8 Av, A20, A21; };

// one dispatch per CRF iteration. Register-only main loop, shared-A G1 (R22),
// 3x16B loads/s-iter. NEW vs R22: 2-DEEP load prefetch via 3 operand slots
// (period-3 rotation, fully unrolled -> all slot refs compile-time). Loads now
// lead their use by ~2 PKG2 phases (~400cy), fully covering L2 latency.
__global__ __launch_bounds__(FBLOCK, 4) void fused_kernel(
    const float* __restrict__ unaries, const float* __restrict__ feat,
    const float* __restrict__ SW, const float* __restrict__ BW,
    const float* __restrict__ CM, const half8* __restrict__ ajc,
    const _Float16* __restrict__ pf_in, _Float16* __restrict__ pf_out,
    float* __restrict__ out, int is_last) {
    __shared__ float rbuf[16 * 640];   // 40 KB, epilogue only
    int t = threadIdx.x;
    int i0 = blockIdx.x * IBLK;
    int lane = t & 63;
    int w = t >> 6;
    int li = lane & 31;      // i (G1/G2 D col) or j (G1 A row) within 32
    int hs = lane >> 5;      // K-half select
    int cr = li & 15;        // p-row for G2 A-operand (c-rows 16..31 discarded)
    const f32x16 zero16 = {};

    // ---- B1 fragments: b1s = {s-aug quad, 0x4}; b1b = {0x4, b-aug quad} ----
    half8 b1s, b1b;
    {
        int i = i0 + li;
        float g0 = feat[0 * N + i], g1 = feat[1 * N + i], g2 = feat[2 * N + i];
        float g3 = feat[3 * N + i], g4 = feat[4 * N + i], g5 = feat[5 * N + i];
        float h3 = 0.5f * (g0 * g0 + g1 * g1 + g2 * g2);
        float h6v = h3 + 0.5f * (g3 * g3 + g4 * g4 + g5 * g5);
        half4 slo = {(_Float16)g0, (_Float16)g1, (_Float16)g2, (_Float16)0.0f};
        half4 shi = {(_Float16)0.0f, (_Float16)0.0f, (_Float16)1.0f, (_Float16)(-h3 * C3)};
        half4 blo = {(_Float16)g0, (_Float16)g1, (_Float16)g2, (_Float16)g3};
        half4 bhi = {(_Float16)g4, (_Float16)g5, (_Float16)1.0f, (_Float16)(-h6v * LOG2E)};
        half4 sv = hs ? shi : slo;
        half4 bv = hs ? bhi : blo;
        half8 t1 = {sv[0], sv[1], sv[2], sv[3], (_Float16)0.0f, (_Float16)0.0f,
                    (_Float16)0.0f, (_Float16)0.0f};
        half8 t2 = {(_Float16)0.0f, (_Float16)0.0f, (_Float16)0.0f,
                    (_Float16)0.0f, bv[0], bv[1], bv[2], bv[3]};
        b1s = t1;
        b1b = t2;
    }

    f32x16 acc_s = zero16, acc_b = zero16;
    int jw = w * JW;

    // convoy-breaking wave stagger (no sync points in main loop -> persists)
    {
        int ph = w & 3;
        if (ph == 1) __builtin_amdgcn_s_sleep(2);
        else if (ph == 2) __builtin_amdgcn_s_sleep(4);
        else if (ph == 3) __builtin_amdgcn_s_sleep(6);
    }

    // load operands for s-iter K: 3 x 16B vector loads, zero unpack VALU
#define LOADOPS(O, K)                                                          \
    {                                                                          \
        int _j0 = jw + ((K) & (NS - 1)) * 32;                                  \
        int _jt = _j0 >> 4;                                                    \
        O.Av = ajc[(size_t)(_j0 + li) * 2 + hs];                               \
        O.A20 = *(const half8*)&pf_in[(size_t)(_jt * 16 + cr) * 16 + 8 * hs];  \
        O.A21 = *(const half8*)&pf_in[(size_t)((_jt + 1) * 16 + cr) * 16 + 8 * hs]; \
    }
    // shared-A G1: garbage quads are annihilated by B1's zero halves
#define G1(DS, DB, O)                                                          \
    {                                                                          \
        DS = __builtin_amdgcn_mfma_f32_32x32x16_f16(O.Av, b1s, zero16, 0, 0, 0); \
        DB = __builtin_amdgcn_mfma_f32_32x32x16_f16(O.Av, b1b, zero16, 0, 0, 0); \
    }
    // pkexp -> B-frags; G2 interleaved s,b,s,b (two serial acc chains overlap)
#define PKG2(DS, DB, O)                                                        \
    {                                                                          \
        half8 _Bs0 = mk8(pkexp(DS[0], DS[1]), pkexp(DS[2], DS[3]),             \
                         pkexp(DS[4], DS[5]), pkexp(DS[6], DS[7]));            \
        half8 _Bb0 = mk8(pkexp(DB[0], DB[1]), pkexp(DB[2], DB[3]),             \
                         pkexp(DB[4], DB[5]), pkexp(DB[6], DB[7]));            \
        half8 _Bs1 = mk8(pkexp(DS[8], DS[9]), pkexp(DS[10], DS[11]),           \
                         pkexp(DS[12], DS[13]), pkexp(DS[14], DS[15]));        \
        half8 _Bb1 = mk8(pkexp(DB[8], DB[9]), pkexp(DB[10], DB[11]),           \
                         pkexp(DB[12], DB[13]), pkexp(DB[14], DB[15]));        \
        __builtin_amdgcn_s_setprio(1);                                         \
        acc_s = __builtin_amdgcn_mfma_f32_32x32x16_f16(O.A20, _Bs0, acc_s, 0, 0, 0); \
        acc_b = __builtin_amdgcn_mfma_f32_32x32x16_f16(O.A20, _Bb0, acc_b, 0, 0, 0); \
        acc_s = __builtin_amdgcn_mfma_f32_32x32x16_f16(O.A21, _Bs1, acc_s, 0, 0, 0); \
        acc_b = __builtin_amdgcn_mfma_f32_32x32x16_f16(O.A21, _Bb1, acc_b, 0, 0, 0); \
        __builtin_amdgcn_s_setprio(0);                                         \
    }
    // one s-iter: G1 consumes CUR; loads for s-iter K2 land in NXT; PKG2 finishes CUR
#define STEP(CUR, NXT, K2)                                                     \
    G1(ds, db, CUR);                                                           \
    LOADOPS(NXT, K2);                                                          \
    PKG2(ds, db, CUR);

    Ops opA, opB, opC;
    f32x16 ds, db;
    LOADOPS(opA, 0);
    LOADOPS(opB, 1);
    // 16 s-iters, slots period-3 (A,B,C), loads lead by 2 phases
    STEP(opA, opC, 2)
    STEP(opB, opA, 3)
    STEP(opC, opB, 4)
    STEP(opA, opC, 5)
    STEP(opB, opA, 6)
    STEP(opC, opB, 7)
    STEP(opA, opC, 8)
    STEP(opB, opA, 9)
    STEP(opC, opB, 10)
    STEP(opA, opC, 11)
    STEP(opB, opA, 12)
    STEP(opC, opB, 13)
    STEP(opA, opC, 14)
    STEP(opB, opA, 15)
    STEP(opC, opB, 16)   // K2 wraps (&15) -> harmless L2-hit reload
    STEP(opA, opC, 17)

#undef STEP
#undef LOADOPS
#undef G1
#undef PKG2

    // ---- dump valid acc rows to rbuf[w][filter][c][i] (c = (r&3)+8(r>>2)+4hs) ----
    {
        float* rb = rbuf + w * 640;
        if (hs == 0) {
#pragma unroll
            for (int r = 0; r < 4; ++r) {
                rb[r * 32 + li]       = acc_s[r];
                rb[320 + r * 32 + li] = acc_b[r];
            }
            rb[8 * 32 + li] = acc_s[4];
            rb[9 * 32 + li] = acc_s[5];
            rb[320 + 8 * 32 + li] = acc_b[4];
            rb[320 + 9 * 32 + li] = acc_b[5];
        } else {
#pragma unroll
            for (int r = 0; r < 4; ++r) {
                rb[(4 + r) * 32 + li]       = acc_s[r];
                rb[320 + (4 + r) * 32 + li] = acc_b[r];
            }
        }
    }
    __syncthreads();
    if (t < 640) {
        float tot = 0.f;
#pragma unroll
        for (int w2 = 0; w2 < 16; ++w2) tot += rbuf[w2 * 640 + t];
        rbuf[t] = tot;   // slot t read only by thread t (w2=0 term)
    }
    __syncthreads();

    // ---- combine + compatibility + softmax for this block's 32 i's ----
    if (t < IBLK) {
        int i = i0 + t;
        float sp[C], bl[C];
#pragma unroll
        for (int c = 0; c < C; ++c) {
            sp[c] = rbuf[c * 32 + t];
            bl[c] = rbuf[320 + c * 32 + t];
        }
        float msg[C];
#pragma unroll
        for (int c = 0; c < C; ++c) {
            float m = 0.f;
#pragma unroll
            for (int kk = 0; kk < C; ++kk)
                m += SW[c * C + kk] * sp[kk] + BW[c * C + kk] * bl[kk];
            msg[c] = m;
        }
        float qq[C];
#pragma unroll
        for (int c = 0; c < C; ++c) {
            float pw = 0.f;
#pragma unroll
            for (int kk = 0; kk < C; ++kk) pw += CM[c * C + kk] * msg[kk];
            qq[c] = unaries[c * N + i] - pw;
        }
        if (is_last) {
#pragma unroll
            for (int c = 0; c < C; ++c) out[c * N + i] = qq[c];
        } else {
            float m = qq[0];
#pragma unroll
            for (int c = 1; c < C; ++c) m = fmaxf(m, qq[c]);
            float e[C], s = 0.0f;
#pragma unroll
            for (int c = 0; c < C; ++c) {
                e[c] = __builtin_amdgcn_exp2f((qq[c] - m) * LOG2E);
                s += e[c];
            }
            float inv = 1.0f / s;
#pragma unroll
            for (int c = 0; c < C; ++c) pf_out[PFIDX(i, c)] = (_Float16)(e[c] * inv);
        }
    }
}

extern "C" void kernel_launch(void* const* d_in, const int* in_sizes, int n_in,
                              void* d_out, int out_size, void* d_ws, size_t ws_size,
                              hipStream_t stream) {
    const float* unaries = (const float*)d_in[0];   // [10, 8192]
    const float* feat    = (const float*)d_in[1];   // [6, 8192]
    const float* SW      = (const float*)d_in[2];   // [10,10]
    const float* BW      = (const float*)d_in[3];   // [10,10]
    const float* CM      = (const float*)d_in[4];   // [10,10]
    float* out = (float*)d_out;

    char* ws = (char*)d_ws;
    half8* ajc    = (half8*)(ws + WS_AJC);
    _Float16* pf0 = (_Float16*)(ws + WS_PF0);
    _Float16* pf1 = (_Float16*)(ws + WS_PF1);

    init_kernel<<<N / 256, 256, 0, stream>>>(unaries, feat, ajc, pf0, pf1);
    const _Float16* pin = pf0;
    _Float16* pout = pf1;
    for (int it = 1; it <= NUM_ITERS; ++it) {
        fused_kernel<<<NBLK, FBLOCK, 0, stream>>>(
            unaries, feat, SW, BW, CM, ajc, pin, pout, out,
            it == NUM_ITERS ? 1 : 0);
        const _Float16* tmp = pout;
        pout = (_Float16*)pin;
        pin = tmp;
    }
}